// Round 3
// baseline (919.881 us; speedup 1.0000x reference)
//
#include <hip/hip_runtime.h>
#include <hip/hip_fp16.h>

// Problem constants (fixed instance)
#define IHc 128
#define IWc 256
#define OHc 256
#define OWc 512
#define Kc  4
#define Pc  4
#define Bc  4
#define Cc  128

constexpr int Nn  = IHc * IWc;        // 32768 input pixels
constexpr int Ee  = Nn * Kc * Pc;     // 524288 scatter entries
constexpr int Oo  = OHc * OWc;        // 131072 output pixels
constexpr int BC  = Bc * Cc;          // 512 planes
constexpr int NBLK = Oo / 256;        // 512 scan blocks

typedef float    f32x4 __attribute__((ext_vector_type(4)));
typedef unsigned u32x4 __attribute__((ext_vector_type(4)));

static __device__ __forceinline__ unsigned short h_bits(__half h) {
    unsigned short u; __builtin_memcpy(&u, &h, 2); return u;
}
static __device__ __forceinline__ float f_from_hbits(unsigned short u) {
    __half h; __builtin_memcpy(&h, &u, 2); return __half2float(h);
}
static __device__ __forceinline__ float2 h2_to_f2(unsigned u) {
    __half2 h; __builtin_memcpy(&h, &u, 4); return __half22float2(h);
}

// ---------------- Phase 0: build CSR (output -> list of packed (n, w_fp16)) ----------------

__global__ void count_kernel(const int* __restrict__ sm, int* __restrict__ counts) {
    int e = blockIdx.x * blockDim.x + threadIdx.x;
    if (e >= Ee) return;
    int x = __builtin_nontemporal_load(&sm[2 * e + 0]);
    int y = __builtin_nontemporal_load(&sm[2 * e + 1]);
    atomicAdd(&counts[y * OWc + x], 1);
}

__global__ void scan1(const int* __restrict__ counts, int* __restrict__ offsets,
                      int* __restrict__ bsum) {
    __shared__ int s[256];
    int tid = threadIdx.x;
    int i = blockIdx.x * 256 + tid;
    int v = counts[i];
    s[tid] = v;
    __syncthreads();
    for (int off = 1; off < 256; off <<= 1) {
        int t = (tid >= off) ? s[tid - off] : 0;
        __syncthreads();
        s[tid] += t;
        __syncthreads();
    }
    offsets[i] = s[tid] - v;              // block-local exclusive
    if (tid == 255) bsum[blockIdx.x] = s[tid];
}

__global__ void scan2(const int* __restrict__ bsum, int* __restrict__ bsumex) {
    __shared__ int s[NBLK];
    int tid = threadIdx.x;
    int v = bsum[tid];
    s[tid] = v;
    __syncthreads();
    for (int off = 1; off < NBLK; off <<= 1) {
        int t = (tid >= off) ? s[tid - off] : 0;
        __syncthreads();
        s[tid] += t;
        __syncthreads();
    }
    bsumex[tid] = s[tid] - v;             // exclusive block prefix
}

__global__ void fill_kernel(const int* __restrict__ sm, const float* __restrict__ iw,
                            const int* __restrict__ offsets, const int* __restrict__ bsumex,
                            int* __restrict__ cursor, unsigned* __restrict__ entries) {
    int e = blockIdx.x * blockDim.x + threadIdx.x;
    if (e >= Ee) return;
    int x = __builtin_nontemporal_load(&sm[2 * e + 0]);
    int y = __builtin_nontemporal_load(&sm[2 * e + 1]);
    int o = y * OWc + x;
    float w = __builtin_nontemporal_load(&iw[e]) * 0.25f;   // interp_weights / KERNEL_SIZE
    int n = e >> 4;                                         // n = e / (K*P)
    unsigned ent = ((unsigned)n << 16) | (unsigned)h_bits(__float2half_rn(w));
    int pos = atomicAdd(&cursor[o], 1);
    entries[offsets[o] + bsumex[o >> 8] + pos] = ent;
}

// ---------------- Phase T: transpose x (BC, Nn) f32 -> xT (Nn, BC) fp16 ----------------

#define TP 32   // planes per tile
#define TN 256  // n per tile

__global__ __launch_bounds__(256) void transpose_kernel(const float* __restrict__ x,
                                                        __half* __restrict__ xt) {
    __shared__ __half lds[TP][TN];
    int tid = threadIdx.x;
    int n0 = blockIdx.x * TN;
    int p0 = blockIdx.y * TP;
    #pragma unroll
    for (int i = 0; i < TP; ++i) {
        float v = __builtin_nontemporal_load(&x[(size_t)(p0 + i) * Nn + n0 + tid]);
        lds[i][tid] = __float2half_rn(v);
    }
    __syncthreads();
    alignas(16) __half tmp[TP];
    #pragma unroll
    for (int i = 0; i < TP; ++i) tmp[i] = lds[i][tid];
    f32x4* dst = (f32x4*)(xt + (size_t)(n0 + tid) * BC + p0);
    const f32x4* src = (const f32x4*)tmp;
    #pragma unroll
    for (int q = 0; q < TP / 8; ++q) dst[q] = src[q];
}

// ---------------- Phase 1: gather ----------------
// Block = 4 waves, owns TILE_O=32 consecutive output pixels x all 512 planes.
// Wave w owns pixels [8w,8w+8); lane l owns planes [8l,8l+8).
// One global_load_dwordx4 per entry covers all 512 planes (1 KB / wave-instr).
// Waves run independent j-loops after the single staging barrier -> 4x MLP.
// out written with nontemporal stores so the 256 MB stream doesn't evict xT.

#define TILE_O 32
#define SCAP 1024

__global__ __launch_bounds__(256) void gather3(const u32x4* __restrict__ xt4,
                                               const int* __restrict__ offsets,
                                               const int* __restrict__ bsumex,
                                               const unsigned* __restrict__ entries,
                                               float* __restrict__ out) {
    __shared__ int soff[TILE_O + 1];
    __shared__ unsigned sent[SCAP];
    int tid = threadIdx.x;
    int o0 = blockIdx.x * TILE_O;

    if (tid <= TILE_O) {
        int go = o0 + tid;
        soff[tid] = (go < Oo) ? (offsets[go] + bsumex[go >> 8]) : Ee;
    }
    __syncthreads();
    int base = soff[0];
    int L = soff[TILE_O] - base;
    int Ll = (L < SCAP) ? L : SCAP;
    for (int j = tid; j < Ll; j += 256) sent[j] = entries[base + j];
    __syncthreads();

    int w = tid >> 6;     // wave id -> pixels [8w, 8w+8)
    int l = tid & 63;     // lane    -> planes [8l, 8l+8)

    float acc[8][8];
    #pragma unroll
    for (int a = 0; a < 8; ++a)
        #pragma unroll
        for (int b = 0; b < 8; ++b) acc[a][b] = 0.f;

    #pragma unroll
    for (int oi = 0; oi < 8; ++oi) {
        int s = soff[8 * w + oi] - base;
        int e = soff[8 * w + oi + 1] - base;
        for (int j = s; j < e; ++j) {
            unsigned ent = (j < SCAP) ? sent[j] : entries[base + j];
            int n = (int)(ent >> 16);
            float wgt = f_from_hbits((unsigned short)(ent & 0xffffu));
            u32x4 raw = xt4[(size_t)n * 64 + l];   // 16 B = planes 8l..8l+7 (fp16)
            float2 f0 = h2_to_f2(raw.x);
            float2 f1 = h2_to_f2(raw.y);
            float2 f2 = h2_to_f2(raw.z);
            float2 f3 = h2_to_f2(raw.w);
            acc[oi][0] += wgt * f0.x;  acc[oi][1] += wgt * f0.y;
            acc[oi][2] += wgt * f1.x;  acc[oi][3] += wgt * f1.y;
            acc[oi][4] += wgt * f2.x;  acc[oi][5] += wgt * f2.y;
            acc[oi][6] += wgt * f3.x;  acc[oi][7] += wgt * f3.y;
        }
    }

    // register-transpose epilogue: plane p = 8l+q gets 8 consecutive pixels [o0+8w, +8)
    int ob = o0 + 8 * w;
    #pragma unroll
    for (int q = 0; q < 8; ++q) {
        size_t row = (size_t)(8 * l + q) * Oo + ob;
        f32x4 lo = { acc[0][q], acc[1][q], acc[2][q], acc[3][q] };
        f32x4 hi = { acc[4][q], acc[5][q], acc[6][q], acc[7][q] };
        __builtin_nontemporal_store(lo, (f32x4*)(out + row));
        __builtin_nontemporal_store(hi, (f32x4*)(out + row + 4));
    }
}

// ---------------- Fallback (ws too small): correct but slow atomic scatter ----------------

__global__ void fallback_scatter(const float* __restrict__ x, const int* __restrict__ sm,
                                 const float* __restrict__ iw, float* __restrict__ out) {
    int e = blockIdx.x * blockDim.x + threadIdx.x;
    if (e >= Ee) return;
    int ox = sm[2 * e + 0];
    int oy = sm[2 * e + 1];
    int o = oy * OWc + ox;
    int n = e >> 4;
    float w = iw[e] * 0.25f;
    for (int p = 0; p < BC; ++p)
        atomicAdd(&out[(size_t)p * Oo + o], x[(size_t)p * Nn + n] * w);
}

// ---------------- launch ----------------

extern "C" void kernel_launch(void* const* d_in, const int* in_sizes, int n_in,
                              void* d_out, int out_size, void* d_ws, size_t ws_size,
                              hipStream_t stream) {
    const float* x  = (const float*)d_in[0];
    const int*   sm = (const int*)d_in[1];
    const float* iw = (const float*)d_in[2];
    float* out = (float*)d_out;

    // ws layout (bytes):
    //   offsets : (Oo+1)*4 = 524292  @ 0        (pad to 524800)
    //   counts  : Oo*4     = 524288  @ 524800
    //   cursor  : Oo*4     = 524288  @ 1049088
    //   bsum    : NBLK*4   = 2048    @ 1573376
    //   bsumex  : NBLK*4   = 2048    @ 1575424
    //   entries : Ee*4     = 2097152 @ 1577472
    //   xT      : Nn*BC*2  = 33554432@ 3674624  (16B aligned)
    constexpr size_t WS_NEED = 3674624 + (size_t)Nn * BC * 2;
    if (ws_size < WS_NEED) {
        hipMemsetAsync(d_out, 0, (size_t)out_size * sizeof(float), stream);
        fallback_scatter<<<Ee / 256, 256, 0, stream>>>(x, sm, iw, out);
        return;
    }

    char* ws = (char*)d_ws;
    int*      offsets = (int*)(ws + 0);
    int*      counts  = (int*)(ws + 524800);
    int*      cursor  = (int*)(ws + 1049088);
    int*      bsum    = (int*)(ws + 1573376);
    int*      bsumex  = (int*)(ws + 1575424);
    unsigned* entries = (unsigned*)(ws + 1577472);
    __half*   xt      = (__half*)(ws + 3674624);

    hipMemsetAsync(counts, 0, Oo * sizeof(int), stream);
    hipMemsetAsync(cursor, 0, Oo * sizeof(int), stream);

    count_kernel<<<Ee / 256, 256, 0, stream>>>(sm, counts);
    scan1<<<NBLK, 256, 0, stream>>>(counts, offsets, bsum);
    scan2<<<1, NBLK, 0, stream>>>(bsum, bsumex);
    fill_kernel<<<Ee / 256, 256, 0, stream>>>(sm, iw, offsets, bsumex, cursor, entries);

    dim3 tgrid(Nn / TN, BC / TP);
    transpose_kernel<<<tgrid, 256, 0, stream>>>(x, xt);

    gather3<<<Oo / TILE_O, 256, 0, stream>>>((const u32x4*)xt, offsets, bsumex, entries, out);
}

// Round 5
// 326.788 us; speedup vs baseline: 2.8149x; 2.8149x over previous
//
#include <hip/hip_runtime.h>
#include <hip/hip_fp16.h>

// Problem constants (fixed instance)
#define IHc 128
#define IWc 256
#define OHc 256
#define OWc 512
#define Kc  4
#define Pc  4
#define Bc  4
#define Cc  128

constexpr int Nn  = IHc * IWc;        // 32768 input pixels
constexpr int Ee  = Nn * Kc * Pc;     // 524288 scatter entries
constexpr int Oo  = OHc * OWc;        // 131072 output pixels
constexpr int BC  = Bc * Cc;          // 512 planes
constexpr int NBLK = Oo / 256;        // 512 scan blocks

typedef float    f32x4 __attribute__((ext_vector_type(4)));
typedef unsigned u32x4 __attribute__((ext_vector_type(4)));
typedef int      i32x2 __attribute__((ext_vector_type(2)));

static __device__ __forceinline__ unsigned short h_bits(__half h) {
    unsigned short u; __builtin_memcpy(&u, &h, 2); return u;
}
static __device__ __forceinline__ float f_from_hbits(unsigned u) {
    __half h; unsigned short us = (unsigned short)(u & 0xffffu);
    __builtin_memcpy(&h, &us, 2); return __half2float(h);
}
static __device__ __forceinline__ float2 h2_to_f2(unsigned u) {
    __half2 h; __builtin_memcpy(&h, &u, 4); return __half22float2(h);
}

// ---------------- Phase 0: build CSR (output -> list of packed (n, w_fp16)) ----------------

__global__ void count_kernel(const i32x2* __restrict__ sm, int* __restrict__ counts) {
    int e = blockIdx.x * blockDim.x + threadIdx.x;
    if (e >= Ee) return;
    i32x2 xy = __builtin_nontemporal_load(&sm[e]);
    atomicAdd(&counts[xy.y * OWc + xy.x], 1);
}

__global__ void scan1(const int* __restrict__ counts, int* __restrict__ offsets,
                      int* __restrict__ bsum) {
    __shared__ int s[256];
    int tid = threadIdx.x;
    int i = blockIdx.x * 256 + tid;
    int v = counts[i];
    s[tid] = v;
    __syncthreads();
    for (int off = 1; off < 256; off <<= 1) {
        int t = (tid >= off) ? s[tid - off] : 0;
        __syncthreads();
        s[tid] += t;
        __syncthreads();
    }
    offsets[i] = s[tid] - v;              // block-local exclusive
    if (tid == 255) bsum[blockIdx.x] = s[tid];
}

__global__ void scan2(const int* __restrict__ bsum, int* __restrict__ bsumex) {
    __shared__ int s[NBLK];
    int tid = threadIdx.x;
    int v = bsum[tid];
    s[tid] = v;
    __syncthreads();
    for (int off = 1; off < NBLK; off <<= 1) {
        int t = (tid >= off) ? s[tid - off] : 0;
        __syncthreads();
        s[tid] += t;
        __syncthreads();
    }
    bsumex[tid] = s[tid] - v;             // exclusive block prefix
}

// pos via atomicSub on counts (counts still holds per-pixel totals after scan1)
__global__ void fill_kernel(const i32x2* __restrict__ sm, const float* __restrict__ iw,
                            const int* __restrict__ offsets, const int* __restrict__ bsumex,
                            int* __restrict__ counts, unsigned* __restrict__ entries) {
    int e = blockIdx.x * blockDim.x + threadIdx.x;
    if (e >= Ee) return;
    i32x2 xy = __builtin_nontemporal_load(&sm[e]);
    int o = xy.y * OWc + xy.x;
    float w = __builtin_nontemporal_load(&iw[e]) * 0.25f;   // interp_weights / KERNEL_SIZE
    int n = e >> 4;                                         // n = e / (K*P)
    unsigned ent = ((unsigned)n << 16) | (unsigned)h_bits(__float2half_rn(w));
    int pos = atomicSub(&counts[o], 1) - 1;                 // unique slot in [0, count)
    entries[offsets[o] + bsumex[o >> 8] + pos] = ent;
}

// ---------------- Phase T: transpose x (BC, Nn) f32 -> xT (Nn, BC) fp16 ----------------

#define TP 32   // planes per tile
#define TN 256  // n per tile

__global__ __launch_bounds__(256) void transpose_kernel(const float* __restrict__ x,
                                                        __half* __restrict__ xt) {
    __shared__ __half lds[TP][TN];
    int tid = threadIdx.x;
    int n0 = blockIdx.x * TN;
    int p0 = blockIdx.y * TP;
    #pragma unroll
    for (int i = 0; i < TP; ++i) {
        float v = __builtin_nontemporal_load(&x[(size_t)(p0 + i) * Nn + n0 + tid]);
        lds[i][tid] = __float2half_rn(v);
    }
    __syncthreads();
    alignas(16) __half tmp[TP];
    #pragma unroll
    for (int i = 0; i < TP; ++i) tmp[i] = lds[i][tid];
    f32x4* dst = (f32x4*)(xt + (size_t)(n0 + tid) * BC + p0);
    const f32x4* src = (const f32x4*)tmp;
    #pragma unroll
    for (int q = 0; q < TP / 8; ++q) dst[q] = src[q];
}

// ---------------- Phase 1: gather ----------------
// Block = 4 waves, TILE_O=32 consecutive output pixels x all 512 planes.
// Wave w owns pixels [8w,8w+8); lane l owns planes [8l,8l+8).
// One global_load_dwordx4 per entry covers all 512 planes (1 KB / wave-instr).
// Entry loop manually unrolled x4 -> 4 outstanding 16B loads per wave.
// REGULAR stores (no nt): L2 write-combines the 4 waves' partial lines (R2-proven).

#define TILE_O 32
#define SCAP 1024

#define ACC8(oi, raw, wf)                                          \
    {                                                              \
        float2 f0 = h2_to_f2((raw).x), f1 = h2_to_f2((raw).y);     \
        float2 f2 = h2_to_f2((raw).z), f3 = h2_to_f2((raw).w);     \
        acc[oi][0] += (wf) * f0.x;  acc[oi][1] += (wf) * f0.y;     \
        acc[oi][2] += (wf) * f1.x;  acc[oi][3] += (wf) * f1.y;     \
        acc[oi][4] += (wf) * f2.x;  acc[oi][5] += (wf) * f2.y;     \
        acc[oi][6] += (wf) * f3.x;  acc[oi][7] += (wf) * f3.y;     \
    }

__global__ __launch_bounds__(256) void gather4(const u32x4* __restrict__ xt4,
                                               const int* __restrict__ offsets,
                                               const int* __restrict__ bsumex,
                                               const unsigned* __restrict__ entries,
                                               float* __restrict__ out) {
    __shared__ int soff[TILE_O + 1];
    __shared__ unsigned sent[SCAP];
    int tid = threadIdx.x;
    int o0 = blockIdx.x * TILE_O;

    if (tid <= TILE_O) {
        int go = o0 + tid;
        soff[tid] = (go < Oo) ? (offsets[go] + bsumex[go >> 8]) : Ee;
    }
    __syncthreads();
    int base = soff[0];
    int L = soff[TILE_O] - base;
    int Ll = (L < SCAP) ? L : SCAP;
    for (int j = tid; j < Ll; j += 256) sent[j] = entries[base + j];
    __syncthreads();

    int w = tid >> 6;     // wave id -> pixels [8w, 8w+8)
    int l = tid & 63;     // lane    -> planes [8l, 8l+8)
    const u32x4* __restrict__ xrow = xt4 + l;

    float acc[8][8];
    #pragma unroll
    for (int a = 0; a < 8; ++a)
        #pragma unroll
        for (int b = 0; b < 8; ++b) acc[a][b] = 0.f;

#define GLOOP(GET)                                                          \
    _Pragma("unroll")                                                       \
    for (int oi = 0; oi < 8; ++oi) {                                        \
        int s = soff[8 * w + oi] - base;                                    \
        int e = soff[8 * w + oi + 1] - base;                                \
        int j = s;                                                          \
        for (; j + 4 <= e; j += 4) {                                        \
            unsigned e0 = GET(j), e1 = GET(j + 1);                          \
            unsigned e2 = GET(j + 2), e3 = GET(j + 3);                      \
            u32x4 r0 = xrow[(size_t)(e0 >> 16) * 64];                       \
            u32x4 r1 = xrow[(size_t)(e1 >> 16) * 64];                       \
            u32x4 r2 = xrow[(size_t)(e2 >> 16) * 64];                       \
            u32x4 r3 = xrow[(size_t)(e3 >> 16) * 64];                       \
            float w0 = f_from_hbits(e0), w1 = f_from_hbits(e1);             \
            float w2 = f_from_hbits(e2), w3 = f_from_hbits(e3);             \
            ACC8(oi, r0, w0); ACC8(oi, r1, w1);                             \
            ACC8(oi, r2, w2); ACC8(oi, r3, w3);                             \
        }                                                                   \
        for (; j < e; ++j) {                                                \
            unsigned e0 = GET(j);                                           \
            u32x4 r0 = xrow[(size_t)(e0 >> 16) * 64];                       \
            float w0 = f_from_hbits(e0);                                    \
            ACC8(oi, r0, w0);                                               \
        }                                                                   \
    }

    if (L <= SCAP) {
#define GET_L(j) (sent[j])
        GLOOP(GET_L)
#undef GET_L
    } else {
#define GET_M(j) ((j) < SCAP ? sent[j] : entries[base + (j)])
        GLOOP(GET_M)
#undef GET_M
    }
#undef GLOOP

    // epilogue: plane p = 8l+q gets 8 consecutive pixels [o0+8w, +8)
    int ob = o0 + 8 * w;
    #pragma unroll
    for (int q = 0; q < 8; ++q) {
        size_t row = (size_t)(8 * l + q) * Oo + ob;
        f32x4 lo = { acc[0][q], acc[1][q], acc[2][q], acc[3][q] };
        f32x4 hi = { acc[4][q], acc[5][q], acc[6][q], acc[7][q] };
        *(f32x4*)(out + row)     = lo;
        *(f32x4*)(out + row + 4) = hi;
    }
}

// ---------------- Fallback (ws too small): correct but slow atomic scatter ----------------

__global__ void fallback_scatter(const float* __restrict__ x, const int* __restrict__ sm,
                                 const float* __restrict__ iw, float* __restrict__ out) {
    int e = blockIdx.x * blockDim.x + threadIdx.x;
    if (e >= Ee) return;
    int ox = sm[2 * e + 0];
    int oy = sm[2 * e + 1];
    int o = oy * OWc + ox;
    int n = e >> 4;
    float w = iw[e] * 0.25f;
    for (int p = 0; p < BC; ++p)
        atomicAdd(&out[(size_t)p * Oo + o], x[(size_t)p * Nn + n] * w);
}

// ---------------- launch ----------------

extern "C" void kernel_launch(void* const* d_in, const int* in_sizes, int n_in,
                              void* d_out, int out_size, void* d_ws, size_t ws_size,
                              hipStream_t stream) {
    const float* x  = (const float*)d_in[0];
    const int*   sm = (const int*)d_in[1];
    const float* iw = (const float*)d_in[2];
    float* out = (float*)d_out;

    // ws layout (bytes):
    //   offsets : (Oo+1)*4 = 524292  @ 0        (pad to 524800)
    //   counts  : Oo*4     = 524288  @ 524800
    //   bsum    : NBLK*4   = 2048    @ 1049088
    //   bsumex  : NBLK*4   = 2048    @ 1051136
    //   entries : Ee*4     = 2097152 @ 1053184
    //   xT      : Nn*BC*2  = 33554432@ 3150336  (16B aligned)
    constexpr size_t WS_NEED = 3150336 + (size_t)Nn * BC * 2;
    if (ws_size < WS_NEED) {
        (void)hipMemsetAsync(d_out, 0, (size_t)out_size * sizeof(float), stream);
        fallback_scatter<<<Ee / 256, 256, 0, stream>>>(x, sm, iw, out);
        return;
    }

    char* ws = (char*)d_ws;
    int*      offsets = (int*)(ws + 0);
    int*      counts  = (int*)(ws + 524800);
    int*      bsum    = (int*)(ws + 1049088);
    int*      bsumex  = (int*)(ws + 1051136);
    unsigned* entries = (unsigned*)(ws + 1053184);
    __half*   xt      = (__half*)(ws + 3150336);

    (void)hipMemsetAsync(counts, 0, Oo * sizeof(int), stream);

    count_kernel<<<Ee / 256, 256, 0, stream>>>((const i32x2*)sm, counts);
    scan1<<<NBLK, 256, 0, stream>>>(counts, offsets, bsum);
    scan2<<<1, NBLK, 0, stream>>>(bsum, bsumex);
    fill_kernel<<<Ee / 256, 256, 0, stream>>>((const i32x2*)sm, iw, offsets, bsumex,
                                              counts, entries);

    dim3 tgrid(Nn / TN, BC / TP);
    transpose_kernel<<<tgrid, 256, 0, stream>>>(x, xt);

    gather4<<<Oo / TILE_O, 256, 0, stream>>>((const u32x4*)xt, offsets, bsumex, entries, out);
}

// Round 6
// 238.626 us; speedup vs baseline: 3.8549x; 1.3695x over previous
//
#include <hip/hip_runtime.h>
#include <hip/hip_fp16.h>

// Problem constants (fixed instance)
#define IHc 128
#define IWc 256
#define OHc 256
#define OWc 512
#define Kc  4
#define Pc  4
#define Bc  4
#define Cc  128

constexpr int Nn  = IHc * IWc;        // 32768 input pixels
constexpr int Ee  = Nn * Kc * Pc;     // 524288 scatter entries
constexpr int Oo  = OHc * OWc;        // 131072 output pixels
constexpr int BC  = Bc * Cc;          // 512 planes
constexpr int NBLK = Oo / 256;        // 512 scan blocks

typedef float    f32x4 __attribute__((ext_vector_type(4)));
typedef unsigned u32x4 __attribute__((ext_vector_type(4)));
typedef int      i32x2 __attribute__((ext_vector_type(2)));

static __device__ __forceinline__ unsigned short h_bits(__half h) {
    unsigned short u; __builtin_memcpy(&u, &h, 2); return u;
}
static __device__ __forceinline__ float f_from_hbits(unsigned u) {
    __half h; unsigned short us = (unsigned short)(u & 0xffffu);
    __builtin_memcpy(&h, &us, 2); return __half2float(h);
}
static __device__ __forceinline__ float2 h2_to_f2(unsigned u) {
    __half2 h; __builtin_memcpy(&h, &u, 4); return __half22float2(h);
}

// ---------------- Phase 0: build CSR (output -> list of packed (n, w_fp16)) ----------------

__global__ void count_kernel(const i32x2* __restrict__ sm, int* __restrict__ counts) {
    int e = blockIdx.x * blockDim.x + threadIdx.x;
    if (e >= Ee) return;
    i32x2 xy = __builtin_nontemporal_load(&sm[e]);
    atomicAdd(&counts[xy.y * OWc + xy.x], 1);
}

__global__ void scan1(const int* __restrict__ counts, int* __restrict__ offsets,
                      int* __restrict__ bsum) {
    __shared__ int s[256];
    int tid = threadIdx.x;
    int i = blockIdx.x * 256 + tid;
    int v = counts[i];
    s[tid] = v;
    __syncthreads();
    for (int off = 1; off < 256; off <<= 1) {
        int t = (tid >= off) ? s[tid - off] : 0;
        __syncthreads();
        s[tid] += t;
        __syncthreads();
    }
    offsets[i] = s[tid] - v;              // block-local exclusive
    if (tid == 255) bsum[blockIdx.x] = s[tid];
}

__global__ void scan2(const int* __restrict__ bsum, int* __restrict__ bsumex) {
    __shared__ int s[NBLK];
    int tid = threadIdx.x;
    int v = bsum[tid];
    s[tid] = v;
    __syncthreads();
    for (int off = 1; off < NBLK; off <<= 1) {
        int t = (tid >= off) ? s[tid - off] : 0;
        __syncthreads();
        s[tid] += t;
        __syncthreads();
    }
    bsumex[tid] = s[tid] - v;             // exclusive block prefix
}

// pos via atomicSub on counts (counts still holds per-pixel totals after scan1)
__global__ void fill_kernel(const i32x2* __restrict__ sm, const float* __restrict__ iw,
                            const int* __restrict__ offsets, const int* __restrict__ bsumex,
                            int* __restrict__ counts, unsigned* __restrict__ entries) {
    int e = blockIdx.x * blockDim.x + threadIdx.x;
    if (e >= Ee) return;
    i32x2 xy = __builtin_nontemporal_load(&sm[e]);
    int o = xy.y * OWc + xy.x;
    float w = __builtin_nontemporal_load(&iw[e]) * 0.25f;   // interp_weights / KERNEL_SIZE
    int n = e >> 4;                                         // n = e / (K*P)
    unsigned ent = ((unsigned)n << 16) | (unsigned)h_bits(__float2half_rn(w));
    int pos = atomicSub(&counts[o], 1) - 1;                 // unique slot in [0, count)
    entries[offsets[o] + bsumex[o >> 8] + pos] = ent;
}

// ---------------- Phase T: transpose x (BC, Nn) f32 -> xT (Nn, BC) fp16 ----------------

#define TP 32   // planes per tile
#define TN 256  // n per tile

__global__ __launch_bounds__(256) void transpose_kernel(const float* __restrict__ x,
                                                        __half* __restrict__ xt) {
    __shared__ __half lds[TP][TN];
    int tid = threadIdx.x;
    int n0 = blockIdx.x * TN;
    int p0 = blockIdx.y * TP;
    #pragma unroll
    for (int i = 0; i < TP; ++i) {
        float v = __builtin_nontemporal_load(&x[(size_t)(p0 + i) * Nn + n0 + tid]);
        lds[i][tid] = __float2half_rn(v);
    }
    __syncthreads();
    alignas(16) __half tmp[TP];
    #pragma unroll
    for (int i = 0; i < TP; ++i) tmp[i] = lds[i][tid];
    f32x4* dst = (f32x4*)(xt + (size_t)(n0 + tid) * BC + p0);
    const f32x4* src = (const f32x4*)tmp;
    #pragma unroll
    for (int q = 0; q < TP / 8; ++q) dst[q] = src[q];
}

// ---------------- Phase 1: gather ----------------
// Block = 4 waves, TILE_O=32 consecutive output pixels x all 512 planes.
// Wave w owns pixels [8w,8w+8); lane l owns planes [8l,8l+8).
// One global_load_dwordx4 per entry covers all 512 planes (1 KB / wave-instr),
// entry loop unrolled x4 -> 4 outstanding loads per wave (FETCH-verified in R5).
// Epilogue: LDS transpose in two 256-plane chunks so each thread writes a FULL
// 128 B output line sequentially (the R2-proven clean write pattern).

#define TILE_O 32
#define SCAP 1024

#define ACC8(oi, raw, wf)                                          \
    {                                                              \
        float2 f0 = h2_to_f2((raw).x), f1 = h2_to_f2((raw).y);     \
        float2 f2 = h2_to_f2((raw).z), f3 = h2_to_f2((raw).w);     \
        acc[oi][0] += (wf) * f0.x;  acc[oi][1] += (wf) * f0.y;     \
        acc[oi][2] += (wf) * f1.x;  acc[oi][3] += (wf) * f1.y;     \
        acc[oi][4] += (wf) * f2.x;  acc[oi][5] += (wf) * f2.y;     \
        acc[oi][6] += (wf) * f3.x;  acc[oi][7] += (wf) * f3.y;     \
    }

__global__ __launch_bounds__(256) void gather5(const u32x4* __restrict__ xt4,
                                               const int* __restrict__ offsets,
                                               const int* __restrict__ bsumex,
                                               const unsigned* __restrict__ entries,
                                               float* __restrict__ out) {
    __shared__ int soff[TILE_O + 1];
    __shared__ unsigned sent[SCAP];
    __shared__ float tbuf[TILE_O][256];   // 32 KB transpose staging (one plane-chunk)

    int tid = threadIdx.x;
    int o0 = blockIdx.x * TILE_O;

    if (tid <= TILE_O) {
        int go = o0 + tid;
        soff[tid] = (go < Oo) ? (offsets[go] + bsumex[go >> 8]) : Ee;
    }
    __syncthreads();
    int base = soff[0];
    int L = soff[TILE_O] - base;
    int Ll = (L < SCAP) ? L : SCAP;
    for (int j = tid; j < Ll; j += 256) sent[j] = entries[base + j];
    __syncthreads();

    int w = tid >> 6;     // wave id -> pixels [8w, 8w+8)
    int l = tid & 63;     // lane    -> planes [8l, 8l+8)
    const u32x4* __restrict__ xrow = xt4 + l;

    float acc[8][8];
    #pragma unroll
    for (int a = 0; a < 8; ++a)
        #pragma unroll
        for (int b = 0; b < 8; ++b) acc[a][b] = 0.f;

#define GLOOP(GET)                                                          \
    _Pragma("unroll")                                                       \
    for (int oi = 0; oi < 8; ++oi) {                                        \
        int s = soff[8 * w + oi] - base;                                    \
        int e = soff[8 * w + oi + 1] - base;                                \
        int j = s;                                                          \
        for (; j + 4 <= e; j += 4) {                                        \
            unsigned e0 = GET(j), e1 = GET(j + 1);                          \
            unsigned e2 = GET(j + 2), e3 = GET(j + 3);                      \
            u32x4 r0 = xrow[(size_t)(e0 >> 16) * 64];                       \
            u32x4 r1 = xrow[(size_t)(e1 >> 16) * 64];                       \
            u32x4 r2 = xrow[(size_t)(e2 >> 16) * 64];                       \
            u32x4 r3 = xrow[(size_t)(e3 >> 16) * 64];                       \
            float w0 = f_from_hbits(e0), w1 = f_from_hbits(e1);             \
            float w2 = f_from_hbits(e2), w3 = f_from_hbits(e3);             \
            ACC8(oi, r0, w0); ACC8(oi, r1, w1);                             \
            ACC8(oi, r2, w2); ACC8(oi, r3, w3);                             \
        }                                                                   \
        for (; j < e; ++j) {                                                \
            unsigned e0 = GET(j);                                           \
            u32x4 r0 = xrow[(size_t)(e0 >> 16) * 64];                       \
            float w0 = f_from_hbits(e0);                                    \
            ACC8(oi, r0, w0);                                               \
        }                                                                   \
    }

    if (L <= SCAP) {
#define GET_L(j) (sent[j])
        GLOOP(GET_L)
#undef GET_L
    } else {
#define GET_M(j) ((j) < SCAP ? sent[j] : entries[base + (j)])
        GLOOP(GET_M)
#undef GET_M
    }
#undef GLOOP

    // ---- epilogue: two plane-chunks of 256; full-line stores per thread ----
    #pragma unroll
    for (int c = 0; c < 2; ++c) {
        __syncthreads();                       // tbuf free (main loop / prev chunk done)
        if ((l >> 5) == c) {                   // lanes holding planes [256c, 256c+256)
            int lp = (l & 31) * 8;             // plane_local base = 8*(l-32c)
            #pragma unroll
            for (int oi = 0; oi < 8; ++oi) {
                float* dst = &tbuf[8 * w + oi][lp];
                f32x4 lo = { acc[oi][0], acc[oi][1], acc[oi][2], acc[oi][3] };
                f32x4 hi = { acc[oi][4], acc[oi][5], acc[oi][6], acc[oi][7] };
                *(f32x4*)dst = lo;
                *(f32x4*)(dst + 4) = hi;
            }
        }
        __syncthreads();
        // thread tid owns plane 256c+tid: read its 32-pixel column, write full line
        float* orow = out + (size_t)(256 * c + tid) * Oo + o0;
        #pragma unroll
        for (int k = 0; k < 8; ++k) {
            f32x4 v = { tbuf[4 * k + 0][tid], tbuf[4 * k + 1][tid],
                        tbuf[4 * k + 2][tid], tbuf[4 * k + 3][tid] };
            *(f32x4*)(orow + 4 * k) = v;
        }
    }
}

// ---------------- Fallback (ws too small): correct but slow atomic scatter ----------------

__global__ void fallback_scatter(const float* __restrict__ x, const int* __restrict__ sm,
                                 const float* __restrict__ iw, float* __restrict__ out) {
    int e = blockIdx.x * blockDim.x + threadIdx.x;
    if (e >= Ee) return;
    int ox = sm[2 * e + 0];
    int oy = sm[2 * e + 1];
    int o = oy * OWc + ox;
    int n = e >> 4;
    float w = iw[e] * 0.25f;
    for (int p = 0; p < BC; ++p)
        atomicAdd(&out[(size_t)p * Oo + o], x[(size_t)p * Nn + n] * w);
}

// ---------------- launch ----------------

extern "C" void kernel_launch(void* const* d_in, const int* in_sizes, int n_in,
                              void* d_out, int out_size, void* d_ws, size_t ws_size,
                              hipStream_t stream) {
    const float* x  = (const float*)d_in[0];
    const int*   sm = (const int*)d_in[1];
    const float* iw = (const float*)d_in[2];
    float* out = (float*)d_out;

    // ws layout (bytes):
    //   offsets : (Oo+1)*4 = 524292  @ 0        (pad to 524800)
    //   counts  : Oo*4     = 524288  @ 524800
    //   bsum    : NBLK*4   = 2048    @ 1049088
    //   bsumex  : NBLK*4   = 2048    @ 1051136
    //   entries : Ee*4     = 2097152 @ 1053184
    //   xT      : Nn*BC*2  = 33554432@ 3150336  (16B aligned)
    constexpr size_t WS_NEED = 3150336 + (size_t)Nn * BC * 2;
    if (ws_size < WS_NEED) {
        (void)hipMemsetAsync(d_out, 0, (size_t)out_size * sizeof(float), stream);
        fallback_scatter<<<Ee / 256, 256, 0, stream>>>(x, sm, iw, out);
        return;
    }

    char* ws = (char*)d_ws;
    int*      offsets = (int*)(ws + 0);
    int*      counts  = (int*)(ws + 524800);
    int*      bsum    = (int*)(ws + 1049088);
    int*      bsumex  = (int*)(ws + 1051136);
    unsigned* entries = (unsigned*)(ws + 1053184);
    __half*   xt      = (__half*)(ws + 3150336);

    (void)hipMemsetAsync(counts, 0, Oo * sizeof(int), stream);

    count_kernel<<<Ee / 256, 256, 0, stream>>>((const i32x2*)sm, counts);
    scan1<<<NBLK, 256, 0, stream>>>(counts, offsets, bsum);
    scan2<<<1, NBLK, 0, stream>>>(bsum, bsumex);
    fill_kernel<<<Ee / 256, 256, 0, stream>>>((const i32x2*)sm, iw, offsets, bsumex,
                                              counts, entries);

    dim3 tgrid(Nn / TN, BC / TP);
    transpose_kernel<<<tgrid, 256, 0, stream>>>(x, xt);

    gather5<<<Oo / TILE_O, 256, 0, stream>>>((const u32x4*)xt, offsets, bsumex, entries, out);
}